// Round 1
// baseline (639.466 us; speedup 1.0000x reference)
//
#include <hip/hip_runtime.h>

#define NGROUPS 131072
#define H 128
#define SG 3            // group size
#define NHEADS 4
#define HD 32
#define GB 16           // groups per block
#define MR 48           // rows per block (= GB*SG, 3 MFMA row-tiles of 16)
#define NT 256          // threads per block (4 waves)
#define XP 132          // xdyn row stride (floats), pad for LDS banks
#define BP 136          // bf16 buffer row stride, pad for LDS banks
#define NLAYERS 2

typedef unsigned short u16;
typedef __bf16 bf16x8 __attribute__((ext_vector_type(8)));
typedef float floatx4 __attribute__((ext_vector_type(4)));

__device__ __forceinline__ float bf2f(u16 u) {
  union { unsigned int i; float f; } c; c.i = ((unsigned int)u) << 16; return c.f;
}
__device__ __forceinline__ u16 f2bf(float f) {
  union { float f; unsigned int i; } c; c.f = f;
  unsigned int x = c.i;
  x += 0x7fffu + ((x >> 16) & 1u);   // round-to-nearest-even
  return (u16)(x >> 16);
}

// ---- weight convert + transpose: wt[slot][n][k] = W[slot][k][n] as bf16 ----
// slots: 0 = Ws; 1+4l+{0,1,2,3} = Wq/Wk/Wv/Wo of layer l. 9*16384 elements.
__global__ void wconv_kernel(const float* __restrict__ Ws, const float* __restrict__ Wq,
                             const float* __restrict__ Wk, const float* __restrict__ Wv,
                             const float* __restrict__ Wo, u16* __restrict__ wt) {
  int idx = blockIdx.x * 256 + threadIdx.x;      // grid sized exactly
  int slot = idx >> 14;
  int rem = idx & 16383;
  int n = rem >> 7, k = rem & 127;
  const float* src;
  if (slot == 0) src = Ws;
  else {
    int l = (slot - 1) >> 2, t = (slot - 1) & 3;
    const float* base = (t == 0) ? Wq : (t == 1) ? Wk : (t == 2) ? Wv : Wo;
    src = base + l * (H * H);
  }
  wt[idx] = f2bf(src[k * H + n]);
}

// ---- one [48,128] @ [128,128] stage, 16x16x32 bf16 MFMA ----
// MODE 0: dst = bf16(relu(acc+bias)); MODE 1: dst = bf16(acc+bias)
// MODE 2: xdyn += beta*(acc+bias); xbf = bf16(xdyn)
template <int MODE>
__device__ __forceinline__ void gemm_stage(
    const u16* __restrict__ A,     // LDS [MR][BP] bf16
    const u16* __restrict__ Bw,    // global transposed weight [128][128] bf16
    const float* __restrict__ bias,// global [128] fp32
    u16* __restrict__ dst,         // LDS [MR][BP] (MODE 0/1)
    float* __restrict__ xdyn,      // LDS [MR][XP] (MODE 2)
    u16* __restrict__ xbf,         // LDS [MR][BP] (MODE 2)
    float beta)
{
  const int lane = threadIdx.x & 63;
  const int wave = threadIdx.x >> 6;
  const int m0 = lane & 15;            // A row / B,C col within tile
  const int q8 = (lane >> 4) << 3;     // k sub-offset within K=32 slice

  // A fragments: 3 row-tiles x 4 k-steps, reused for both col-tiles
  bf16x8 af[3][4];
#pragma unroll
  for (int rt = 0; rt < 3; rt++)
#pragma unroll
    for (int kk = 0; kk < 4; kk++)
      af[rt][kk] = *reinterpret_cast<const bf16x8*>(A + (rt * 16 + m0) * BP + kk * 32 + q8);

  // B fragments: wave w owns col-tiles w and w+4 (cols w*16.. and 64+w*16..)
  const int col0 = wave * 16 + m0;
  const int col1 = col0 + 64;
  bf16x8 bfr[2][4];
#pragma unroll
  for (int kk = 0; kk < 4; kk++) {
    bfr[0][kk] = *reinterpret_cast<const bf16x8*>(Bw + col0 * H + kk * 32 + q8);
    bfr[1][kk] = *reinterpret_cast<const bf16x8*>(Bw + col1 * H + kk * 32 + q8);
  }

  floatx4 acc[2][3];
#pragma unroll
  for (int c = 0; c < 2; c++)
#pragma unroll
    for (int rt = 0; rt < 3; rt++)
      acc[c][rt] = (floatx4){0.f, 0.f, 0.f, 0.f};

#pragma unroll
  for (int kk = 0; kk < 4; kk++)
#pragma unroll
    for (int c = 0; c < 2; c++)
#pragma unroll
      for (int rt = 0; rt < 3; rt++)
        acc[c][rt] = __builtin_amdgcn_mfma_f32_16x16x32_bf16(af[rt][kk], bfr[c][kk], acc[c][rt], 0, 0, 0);

  // epilogue: C/D layout col=lane&15, row=(lane>>4)*4+r
  const int rbase = (lane >> 4) << 2;
#pragma unroll
  for (int c = 0; c < 2; c++) {
    const int col = (c == 0) ? col0 : col1;
    const float b = bias[col];
#pragma unroll
    for (int rt = 0; rt < 3; rt++) {
#pragma unroll
      for (int r = 0; r < 4; r++) {
        const int row = rt * 16 + rbase + r;
        float v = acc[c][rt][r] + b;
        if (MODE == 0) v = fmaxf(v, 0.f);
        if (MODE <= 1) {
          dst[row * BP + col] = f2bf(v);
        } else {
          float nv = xdyn[row * XP + col] + beta * v;
          xdyn[row * XP + col] = nv;
          xbf[row * BP + col] = f2bf(nv);
        }
      }
    }
  }
}

__global__ void __launch_bounds__(NT, 2)
dango_kernel(const float* __restrict__ x, const u16* __restrict__ wt,
             const float* __restrict__ bs, const float* __restrict__ bq,
             const float* __restrict__ bk, const float* __restrict__ bv,
             const float* __restrict__ bo, const float* __restrict__ beta,
             const float* __restrict__ Wp, const float* __restrict__ bp,
             float* __restrict__ out)
{
  // 79,296 B total -> 2 blocks/CU
  __shared__ float xdyn[MR][XP];     // fp32 residual stream
  __shared__ u16 xbf[MR][BP];        // bf16 mirror (MFMA A operand)
  __shared__ u16 qbuf[MR][BP];       // Q, later V
  __shared__ u16 kbuf[MR][BP];       // K, later attention-out
  __shared__ u16 stat[MR][BP];       // static embedding (bf16)
  __shared__ float attnw[GB][NHEADS][SG][2];
  __shared__ float rowsc[MR];

  const int tid = threadIdx.x;
  const int row0 = blockIdx.x * MR;

  // ---- load x tile (coalesced float4), mirror to bf16 ----
  for (int ch = tid; ch < MR * 32; ch += NT) {
    int r = ch >> 5, c0 = (ch & 31) << 2;
    float4 v = *reinterpret_cast<const float4*>(x + (size_t)(row0 + r) * H + c0);
    *reinterpret_cast<float4*>(&xdyn[r][c0]) = v;
    ushort4 u;
    u.x = f2bf(v.x); u.y = f2bf(v.y); u.z = f2bf(v.z); u.w = f2bf(v.w);
    *reinterpret_cast<ushort4*>(&xbf[r][c0]) = u;
  }
  __syncthreads();

  // ---- static = relu(x @ Ws + bs) ----
  gemm_stage<0>(&xbf[0][0], wt, bs, &stat[0][0], nullptr, nullptr, 0.f);
  // (no barrier needed: stat not read until the end; next stages only read xbf)

  for (int l = 0; l < NLAYERS; l++) {
    const u16* wq = wt + (size_t)(1 + l * 4 + 0) * H * H;
    const u16* wk = wt + (size_t)(1 + l * 4 + 1) * H * H;
    const u16* wv = wt + (size_t)(1 + l * 4 + 2) * H * H;
    const u16* wo = wt + (size_t)(1 + l * 4 + 3) * H * H;
    const float betal = beta[l];

    gemm_stage<1>(&xbf[0][0], wq, bq + l * H, &qbuf[0][0], nullptr, nullptr, 0.f);
    gemm_stage<1>(&xbf[0][0], wk, bk + l * H, &kbuf[0][0], nullptr, nullptr, 0.f);
    __syncthreads();

    // ---- scores + 2-way softmax (self excluded), exact ----
    if (tid < GB * NHEADS * SG) {
      int g = tid / (NHEADS * SG);
      int rem = tid % (NHEADS * SG);
      int h = rem / SG;
      int i = rem % SG;
      int j0 = (i == 0) ? 1 : 0;
      int j1 = (i == 2) ? 1 : 2;
      const u16* qp = &qbuf[g * 3 + i][h * HD];
      const u16* k0p = &kbuf[g * 3 + j0][h * HD];
      const u16* k1p = &kbuf[g * 3 + j1][h * HD];
      float s0 = 0.f, s1 = 0.f;
#pragma unroll
      for (int d = 0; d < HD; d++) {
        float qv = bf2f(qp[d]);
        s0 += qv * bf2f(k0p[d]);
        s1 += qv * bf2f(k1p[d]);
      }
      s0 *= 0.17677669529663687f;   // 1/sqrt(32)
      s1 *= 0.17677669529663687f;
      float mx = fmaxf(s0, s1);
      float e0 = __expf(s0 - mx), e1 = __expf(s1 - mx);
      float inv = 1.f / (e0 + e1);
      attnw[g][h][i][0] = e0 * inv;
      attnw[g][h][i][1] = e1 * inv;
    }
    __syncthreads();

    // ---- V = x @ Wv + bv (overwrites qbuf; safe after barrier) ----
    gemm_stage<1>(&xbf[0][0], wv, bv + l * H, &qbuf[0][0], nullptr, nullptr, 0.f);
    __syncthreads();

    // ---- attention-out = attn @ V (per head), into kbuf ----
    for (int ch = tid; ch < MR * 16; ch += NT) {
      int r = ch >> 4, c0 = (ch & 15) << 3;
      int g = r / 3, i = r - g * 3, h = c0 >> 5;
      int j0 = (i == 0) ? 1 : 0;
      int j1 = (i == 2) ? 1 : 2;
      float a0 = attnw[g][h][i][0], a1 = attnw[g][h][i][1];
      const u16* v0 = &qbuf[g * 3 + j0][c0];
      const u16* v1 = &qbuf[g * 3 + j1][c0];
#pragma unroll
      for (int d = 0; d < 8; d++)
        kbuf[r][c0 + d] = f2bf(a0 * bf2f(v0[d]) + a1 * bf2f(v1[d]));
    }
    __syncthreads();

    // ---- ReZero: xdyn += beta * (ao @ Wo + bo); refresh bf16 mirror ----
    gemm_stage<2>(&kbuf[0][0], wo, bo + l * H, nullptr, &xdyn[0][0], &xbf[0][0], betal);
    __syncthreads();
  }

  // ---- gene scores: sum_c (dyn-static)^2 * Wp[c], then per-group mean ----
  const float bpv = bp[0];
  for (int ch = tid; ch < MR * 16; ch += NT) {
    int r = ch >> 4, c0 = (ch & 15) << 3;
    float part = 0.f;
#pragma unroll
    for (int d = 0; d < 8; d++) {
      float diff = xdyn[r][c0 + d] - bf2f(stat[r][c0 + d]);
      part += diff * diff * Wp[c0 + d];
    }
    // 16 consecutive lanes share the same row r
    part += __shfl_xor(part, 1, 64);
    part += __shfl_xor(part, 2, 64);
    part += __shfl_xor(part, 4, 64);
    part += __shfl_xor(part, 8, 64);
    if ((tid & 15) == 0) rowsc[r] = part;
  }
  __syncthreads();
  if (tid < GB) {
    float s = (rowsc[tid * 3] + rowsc[tid * 3 + 1] + rowsc[tid * 3 + 2]) * (1.f / 3.f) + bpv;
    out[blockIdx.x * GB + tid] = s;
  }
}

extern "C" void kernel_launch(void* const* d_in, const int* in_sizes, int n_in,
                              void* d_out, int out_size, void* d_ws, size_t ws_size,
                              hipStream_t stream) {
  const float* x    = (const float*)d_in[0];
  // d_in[1] = batch ids: deterministic repeat(arange(G),3) -> not needed
  const float* Ws   = (const float*)d_in[2];
  const float* bs   = (const float*)d_in[3];
  const float* Wq   = (const float*)d_in[4];
  const float* bq   = (const float*)d_in[5];
  const float* Wk   = (const float*)d_in[6];
  const float* bk   = (const float*)d_in[7];
  const float* Wv   = (const float*)d_in[8];
  const float* bv   = (const float*)d_in[9];
  const float* Wo   = (const float*)d_in[10];
  const float* bo   = (const float*)d_in[11];
  const float* beta = (const float*)d_in[12];
  const float* Wp   = (const float*)d_in[13];
  const float* bp   = (const float*)d_in[14];
  float* out = (float*)d_out;
  u16* wt = (u16*)d_ws;   // 9 * 128*128 bf16 = 294,912 B

  // ws is re-poisoned before every launch -> convert every call
  wconv_kernel<<<576, 256, 0, stream>>>(Ws, Wq, Wk, Wv, Wo, wt);
  dango_kernel<<<NGROUPS / GB, NT, 0, stream>>>(x, wt, bs, bq, bk, bv, bo, beta, Wp, bp, out);
}

// Round 2
// 616.808 us; speedup vs baseline: 1.0367x; 1.0367x over previous
//
#include <hip/hip_runtime.h>

#define NGROUPS 131072
#define H 128
#define SG 3            // group size
#define NHEADS 4
#define HD 32
#define GB 16           // groups per block
#define MR 48           // rows per block (= GB*SG, 3 MFMA row-tiles of 16)
#define NT 512          // threads per block (8 waves)
#define BP 136          // bf16 buffer row stride (elements), LDS bank pad
#define NLAYERS 2

typedef unsigned short u16;
typedef __bf16 bf16x8 __attribute__((ext_vector_type(8)));
typedef float floatx4 __attribute__((ext_vector_type(4)));

__device__ __forceinline__ float bf2f(u16 u) {
  union { unsigned int i; float f; } c; c.i = ((unsigned int)u) << 16; return c.f;
}
__device__ __forceinline__ u16 f2bf(float f) {
  union { float f; unsigned int i; } c; c.f = f;
  unsigned int x = c.i;
  x += 0x7fffu + ((x >> 16) & 1u);   // round-to-nearest-even
  return (u16)(x >> 16);
}

// ---- weight convert + transpose: wt[slot][n][k] = W[slot][k][n] as bf16 ----
__global__ void wconv_kernel(const float* __restrict__ Ws, const float* __restrict__ Wq,
                             const float* __restrict__ Wk, const float* __restrict__ Wv,
                             const float* __restrict__ Wo, u16* __restrict__ wt) {
  int idx = blockIdx.x * 256 + threadIdx.x;      // grid sized exactly (9*16384/256)
  int slot = idx >> 14;
  int rem = idx & 16383;
  int n = rem >> 7, k = rem & 127;
  const float* src;
  if (slot == 0) src = Ws;
  else {
    int l = (slot - 1) >> 2, t = (slot - 1) & 3;
    const float* base = (t == 0) ? Wq : (t == 1) ? Wk : (t == 2) ? Wv : Wo;
    src = base + l * (H * H);
  }
  wt[idx] = f2bf(src[k * H + n]);
}

// load 12 A-fragments (3 row-tiles x 4 k-steps) from an LDS bf16 buffer
__device__ __forceinline__ void load_af(const u16* __restrict__ buf, int m0, int q8,
                                        bf16x8 af[3][4]) {
#pragma unroll
  for (int rt = 0; rt < 3; rt++)
#pragma unroll
    for (int kk = 0; kk < 4; kk++)
      af[rt][kk] = *reinterpret_cast<const bf16x8*>(buf + (rt * 16 + m0) * BP + kk * 32 + q8);
}

// one [48,128] @ [128,16] sub-stage for this wave's col-tile
__device__ __forceinline__ void mm_sub(const bf16x8 af[3][4], const u16* __restrict__ W,
                                       int col, int q8, floatx4 acc[3]) {
  bf16x8 b[4];
#pragma unroll
  for (int kk = 0; kk < 4; kk++)
    b[kk] = *reinterpret_cast<const bf16x8*>(W + col * H + kk * 32 + q8);
#pragma unroll
  for (int rt = 0; rt < 3; rt++)
    acc[rt] = (floatx4){0.f, 0.f, 0.f, 0.f};
#pragma unroll
  for (int kk = 0; kk < 4; kk++)
#pragma unroll
    for (int rt = 0; rt < 3; rt++)
      acc[rt] = __builtin_amdgcn_mfma_f32_16x16x32_bf16(af[rt][kk], b[kk], acc[rt], 0, 0, 0);
}

// store acc+bias as bf16 into LDS buffer (C layout: col fixed, row = rt*16+qi*4+r)
__device__ __forceinline__ void store_bf(u16* __restrict__ buf, const floatx4 acc[3],
                                         float bias, int col, int qi) {
#pragma unroll
  for (int rt = 0; rt < 3; rt++)
#pragma unroll
    for (int r = 0; r < 4; r++)
      buf[(rt * 16 + qi * 4 + r) * BP + col] = f2bf(acc[rt][r] + bias);
}

__global__ void __launch_bounds__(NT, 4)
dango_kernel(const float* __restrict__ x, const u16* __restrict__ wt,
             const float* __restrict__ bs, const float* __restrict__ bq,
             const float* __restrict__ bk, const float* __restrict__ bv,
             const float* __restrict__ bo, const float* __restrict__ beta,
             const float* __restrict__ Wp, const float* __restrict__ bp,
             float* __restrict__ out)
{
  // 42,432 B LDS -> LDS allows 3 blocks/CU; wave budget (8 waves, VGPR<=128) -> 2 blocks/CU
  __shared__ u16 xbf[MR][BP];        // residual bf16 mirror; also V buffer mid-layer
  __shared__ u16 qbuf[MR][BP];       // Q, later attention-out
  __shared__ u16 kbuf[MR][BP];       // K
  __shared__ float attnw[GB][NHEADS][SG][2];
  __shared__ float rowsc[MR][9];     // per-row partials, one col per wave (+pad)

  const int tid = threadIdx.x;
  const int lane = tid & 63;
  const int wave = tid >> 6;         // 0..7, owns cols wave*16..wave*16+15
  const int m0 = lane & 15;
  const int qi = lane >> 4;          // 0..3
  const int q8 = qi << 3;
  const int col = wave * 16 + m0;    // this thread's output column (C layout)
  const int row0 = blockIdx.x * MR;

  // ---- init: x -> xdyn regs (C layout) + xbf LDS (bf16) ----
  // loads are 64B-segment coalesced: 16 lanes read 16 consecutive floats of one row
  float xdyn[3][4];
#pragma unroll
  for (int rt = 0; rt < 3; rt++)
#pragma unroll
    for (int r = 0; r < 4; r++) {
      int row = rt * 16 + qi * 4 + r;
      float v = x[(size_t)(row0 + row) * H + col];
      xdyn[rt][r] = v;
      xbf[row][col] = f2bf(v);
    }
  __syncthreads();

  float stat[3][4];
  bf16x8 af[3][4];
  floatx4 acc[3];

  // ---- phase A: static + Q/K/V of layer 0 (A = xbf for all four) ----
  load_af(&xbf[0][0], m0, q8, af);
  __syncthreads();   // all waves must finish reading xbf before V overwrites it

  mm_sub(af, wt, col, q8, acc);                       // static: relu(x@Ws+bs)
  {
    float b = bs[col];
#pragma unroll
    for (int rt = 0; rt < 3; rt++)
#pragma unroll
      for (int r = 0; r < 4; r++)
        stat[rt][r] = fmaxf(acc[rt][r] + b, 0.f);
  }
  mm_sub(af, wt + (size_t)1 * H * H, col, q8, acc);
  store_bf(&qbuf[0][0], acc, bq[col], col, qi);
  mm_sub(af, wt + (size_t)2 * H * H, col, q8, acc);
  store_bf(&kbuf[0][0], acc, bk[col], col, qi);
  mm_sub(af, wt + (size_t)3 * H * H, col, q8, acc);
  store_bf(&xbf[0][0], acc, bv[col], col, qi);        // V overwrites xbf
  __syncthreads();

  for (int l = 0; l < NLAYERS; l++) {
    // ---- scores + 2-way softmax (self excluded), exact ----
    if (tid < GB * NHEADS * SG) {
      int g = tid / (NHEADS * SG);
      int rem = tid % (NHEADS * SG);
      int h = rem / SG;
      int i = rem % SG;
      int j0 = (i == 0) ? 1 : 0;
      int j1 = (i == 2) ? 1 : 2;
      const u16* qp = &qbuf[g * 3 + i][h * HD];
      const u16* k0p = &kbuf[g * 3 + j0][h * HD];
      const u16* k1p = &kbuf[g * 3 + j1][h * HD];
      float s0 = 0.f, s1 = 0.f;
#pragma unroll
      for (int d = 0; d < HD; d++) {
        float qv = bf2f(qp[d]);
        s0 += qv * bf2f(k0p[d]);
        s1 += qv * bf2f(k1p[d]);
      }
      s0 *= 0.17677669529663687f;   // 1/sqrt(32)
      s1 *= 0.17677669529663687f;
      float mx = fmaxf(s0, s1);
      float e0 = __expf(s0 - mx), e1 = __expf(s1 - mx);
      float inv = 1.f / (e0 + e1);
      attnw[g][h][i][0] = e0 * inv;
      attnw[g][h][i][1] = e1 * inv;
    }
    __syncthreads();

    // ---- attention-out = attn @ V : reads xbf(V) + attnw, writes qbuf ----
    for (int ch = tid; ch < MR * 16; ch += NT) {
      int r = ch >> 4, c0 = (ch & 15) << 3;
      int g = r / 3, i = r - g * 3, h = c0 >> 5;
      int j0 = (i == 0) ? 1 : 0;
      int j1 = (i == 2) ? 1 : 2;
      float a0 = attnw[g][h][i][0], a1 = attnw[g][h][i][1];
      const u16* v0 = &xbf[g * 3 + j0][c0];
      const u16* v1 = &xbf[g * 3 + j1][c0];
#pragma unroll
      for (int d = 0; d < 8; d++)
        qbuf[r][c0 + d] = f2bf(a0 * bf2f(v0[d]) + a1 * bf2f(v1[d]));
    }
    __syncthreads();

    // ---- O-projection + ReZero into xdyn regs; refresh xbf with new residual ----
    const u16* wo = wt + (size_t)(1 + l * 4 + 3) * H * H;
    const float betal = beta[l];
    load_af(&qbuf[0][0], m0, q8, af);
    mm_sub(af, wo, col, q8, acc);
    {
      float b = bo[l * H + col];
#pragma unroll
      for (int rt = 0; rt < 3; rt++)
#pragma unroll
        for (int r = 0; r < 4; r++) {
          float nv = xdyn[rt][r] + betal * (acc[rt][r] + b);
          xdyn[rt][r] = nv;
          xbf[(rt * 16 + qi * 4 + r)][col] = f2bf(nv);
        }
    }
    __syncthreads();

    if (l + 1 < NLAYERS) {
      // ---- Q/K/V of layer l+1 (A = xbf) ----
      const u16* wq = wt + (size_t)(1 + (l + 1) * 4 + 0) * H * H;
      const u16* wk = wt + (size_t)(1 + (l + 1) * 4 + 1) * H * H;
      const u16* wv = wt + (size_t)(1 + (l + 1) * 4 + 2) * H * H;
      load_af(&xbf[0][0], m0, q8, af);
      __syncthreads();   // protect xbf reads before V overwrites
      mm_sub(af, wq, col, q8, acc);
      store_bf(&qbuf[0][0], acc, bq[(l + 1) * H + col], col, qi);
      mm_sub(af, wk, col, q8, acc);
      store_bf(&kbuf[0][0], acc, bk[(l + 1) * H + col], col, qi);
      mm_sub(af, wv, col, q8, acc);
      store_bf(&xbf[0][0], acc, bv[(l + 1) * H + col], col, qi);
      __syncthreads();
    }
  }

  // ---- readout: gene score = sum_c (dyn-stat)^2 * Wp[c]; group mean ----
  const float wpc = Wp[col];
  float rv[3][4];
#pragma unroll
  for (int rt = 0; rt < 3; rt++)
#pragma unroll
    for (int r = 0; r < 4; r++) {
      float d = xdyn[rt][r] - stat[rt][r];
      rv[rt][r] = d * d * wpc;
    }
  // reduce across the 16 column-lanes (bits 0..3 of lane)
#pragma unroll
  for (int mask = 1; mask <= 8; mask <<= 1)
#pragma unroll
    for (int rt = 0; rt < 3; rt++)
#pragma unroll
      for (int r = 0; r < 4; r++)
        rv[rt][r] += __shfl_xor(rv[rt][r], mask, 64);
  if (m0 == 0) {
#pragma unroll
    for (int rt = 0; rt < 3; rt++)
#pragma unroll
      for (int r = 0; r < 4; r++)
        rowsc[rt * 16 + qi * 4 + r][wave] = rv[rt][r];
  }
  __syncthreads();
  if (tid < GB) {
    const float bpv = bp[0];
    float s = 0.f;
#pragma unroll
    for (int i = 0; i < SG; i++) {
      int row = tid * 3 + i;
#pragma unroll
      for (int w = 0; w < 8; w++) s += rowsc[row][w];
    }
    out[blockIdx.x * GB + tid] = s * (1.f / 3.f) + bpv;
  }
}

extern "C" void kernel_launch(void* const* d_in, const int* in_sizes, int n_in,
                              void* d_out, int out_size, void* d_ws, size_t ws_size,
                              hipStream_t stream) {
  const float* x    = (const float*)d_in[0];
  // d_in[1] = batch ids: deterministic repeat(arange(G),3) -> not needed
  const float* Ws   = (const float*)d_in[2];
  const float* bs   = (const float*)d_in[3];
  const float* Wq   = (const float*)d_in[4];
  const float* bq   = (const float*)d_in[5];
  const float* Wk   = (const float*)d_in[6];
  const float* bk   = (const float*)d_in[7];
  const float* Wv   = (const float*)d_in[8];
  const float* bv   = (const float*)d_in[9];
  const float* Wo   = (const float*)d_in[10];
  const float* bo   = (const float*)d_in[11];
  const float* beta = (const float*)d_in[12];
  const float* Wp   = (const float*)d_in[13];
  const float* bp   = (const float*)d_in[14];
  float* out = (float*)d_out;
  u16* wt = (u16*)d_ws;   // 9 * 128*128 bf16 = 294,912 B

  // ws is re-poisoned before every launch -> convert every call
  wconv_kernel<<<576, 256, 0, stream>>>(Ws, Wq, Wk, Wv, Wo, wt);
  dango_kernel<<<NGROUPS / GB, NT, 0, stream>>>(x, wt, bs, bq, bk, bv, bo, beta, Wp, bp, out);
}

// Round 3
// 609.267 us; speedup vs baseline: 1.0496x; 1.0124x over previous
//
#include <hip/hip_runtime.h>
#include <hip/hip_bf16.h>

#define NGROUPS 131072
#define H 128
#define SG 3            // group size
#define NHEADS 4
#define HD 32
#define GB 16           // groups per block
#define MR 48           // rows per block (= GB*SG)
#define NT 512          // threads per block (8 waves)
#define BP 136          // bf16 LDS row stride (elements); keeps b128 16B-aligned
#define NLAYERS 2

typedef unsigned short u16;
typedef unsigned int u32;
typedef __bf16 bf16x8 __attribute__((ext_vector_type(8)));
typedef float floatx4 __attribute__((ext_vector_type(4)));

__device__ __forceinline__ float bf2f_lo(u32 u) {
  union { u32 i; float f; } c; c.i = u << 16; return c.f;
}
__device__ __forceinline__ float bf2f_hi(u32 u) {
  union { u32 i; float f; } c; c.i = u & 0xffff0000u; return c.f;
}
// packed f32x2 -> bf16x2 (v_cvt_pk_bf16_f32 on gfx950), RNE
__device__ __forceinline__ u32 f2bf2(float a, float b) {
  __hip_bfloat162 h = __float22bfloat162_rn(make_float2(a, b));
  union { __hip_bfloat162 h; u32 u; } c; c.h = h; return c.u;
}
__device__ __forceinline__ u16 f2bf(float f) {
  union { float f; u32 i; } c; c.f = f;
  u32 x = c.i; x += 0x7fffu + ((x >> 16) & 1u);
  return (u16)(x >> 16);
}

// ---- weight convert + transpose: wt[slot][n][k] = W[slot][k][n] as bf16 ----
__global__ void wconv_kernel(const float* __restrict__ Ws, const float* __restrict__ Wq,
                             const float* __restrict__ Wk, const float* __restrict__ Wv,
                             const float* __restrict__ Wo, u16* __restrict__ wt) {
  int idx = blockIdx.x * 256 + threadIdx.x;      // grid sized exactly (9*16384/256)
  int slot = idx >> 14;
  int rem = idx & 16383;
  int n = rem >> 7, k = rem & 127;
  const float* src;
  if (slot == 0) src = Ws;
  else {
    int l = (slot - 1) >> 2, t = (slot - 1) & 3;
    const float* base = (t == 0) ? Wq : (t == 1) ? Wk : (t == 2) ? Wv : Wo;
    src = base + l * (H * H);
  }
  wt[idx] = f2bf(src[k * H + n]);
}

// load 12 B-fragments (gene rows) from a row-major bf16 LDS buffer
// B[n][k]: n = nt*16+m0, k = kk*32 + qi*8 .. +7
__device__ __forceinline__ void load_bfrag(const u16* __restrict__ buf, int m0, int qi,
                                           bf16x8 bf[3][4]) {
#pragma unroll
  for (int nt = 0; nt < 3; nt++)
#pragma unroll
    for (int kk = 0; kk < 4; kk++)
      bf[nt][kk] = *reinterpret_cast<const bf16x8*>(buf + (nt * 16 + m0) * BP + kk * 32 + qi * 8);
}

// one 128-wide projection: A = weight rows (outcols), B = gene-row frags.
// D[outcol = (lane>>4)*4+r][generow = lane&15] -> thread owns 1 row x 4 cols per nt
__device__ __forceinline__ void proj(const bf16x8 bf[3][4], const u16* __restrict__ W,
                                     int wrow, int qi, floatx4 acc[3]) {
  bf16x8 a[4];
#pragma unroll
  for (int kk = 0; kk < 4; kk++)
    a[kk] = *reinterpret_cast<const bf16x8*>(W + wrow * H + kk * 32 + qi * 8);
#pragma unroll
  for (int nt = 0; nt < 3; nt++)
    acc[nt] = (floatx4){0.f, 0.f, 0.f, 0.f};
#pragma unroll
  for (int kk = 0; kk < 4; kk++)
#pragma unroll
    for (int nt = 0; nt < 3; nt++)
      acc[nt] = __builtin_amdgcn_mfma_f32_16x16x32_bf16(a[kk], bf[nt][kk], acc[nt], 0, 0, 0);
}

// store acc+bias as packed bf16, 4 consecutive cols per row -> one b64 write per nt
__device__ __forceinline__ void store_proj(u16* __restrict__ buf, const floatx4 acc[3],
                                           float4 b4, int m0, int colb) {
#pragma unroll
  for (int nt = 0; nt < 3; nt++) {
    uint2 pp;
    pp.x = f2bf2(acc[nt][0] + b4.x, acc[nt][1] + b4.y);
    pp.y = f2bf2(acc[nt][2] + b4.z, acc[nt][3] + b4.w);
    *reinterpret_cast<uint2*>(buf + (nt * 16 + m0) * BP + colb) = pp;
  }
}

__global__ void __launch_bounds__(NT)
__attribute__((amdgpu_waves_per_eu(4, 4)))   // pin VGPR budget to 128: r2's (512,4) hint made the allocator chase 8 w/EU -> 64 VGPR -> 25 MB scratch spill
dango_kernel(const float* __restrict__ x, const u16* __restrict__ wt,
             const float* __restrict__ bs, const float* __restrict__ bq,
             const float* __restrict__ bk, const float* __restrict__ bv,
             const float* __restrict__ bo, const float* __restrict__ beta,
             const float* __restrict__ Wp, const float* __restrict__ bp,
             float* __restrict__ out)
{
  // ~55.5 KB LDS -> 2 blocks/CU (wave-limited to 2 anyway at 128 VGPR)
  __shared__ __align__(16) u16 xbf[MR][BP];   // residual bf16 mirror
  __shared__ __align__(16) u16 qbuf[MR][BP];  // Q, later attention-out
  __shared__ __align__(16) u16 kbuf[MR][BP];  // K
  __shared__ __align__(16) u16 vbuf[MR][BP];  // V
  __shared__ float attnw[GB][NHEADS][SG][2];
  __shared__ float rowsc[MR][9];

  const int tid = threadIdx.x;
  const int lane = tid & 63;
  const int wave = tid >> 6;          // 0..7: owns outcols wave*16..wave*16+15
  const int m0 = lane & 15;           // gene-row index within nt-tile
  const int qi = lane >> 4;           // 0..3: 4-col window within wave's 16
  const int colb = wave * 16 + qi * 4;
  const int wrow = wave * 16 + m0;    // weight row (outcol) this lane loads
  const int row0 = blockIdx.x * MR;

  float xdyn[3][4];                   // residual, fp32: rows nt*16+m0, cols colb..+3
  u32 statpk[3][2];                   // static embedding, packed bf16

  // ---- init: x -> xdyn regs + xbf mirror (coalesced float4 per lane) ----
#pragma unroll
  for (int nt = 0; nt < 3; nt++) {
    int row = nt * 16 + m0;
    float4 v = *reinterpret_cast<const float4*>(x + (size_t)(row0 + row) * H + colb);
    xdyn[nt][0] = v.x; xdyn[nt][1] = v.y; xdyn[nt][2] = v.z; xdyn[nt][3] = v.w;
    uint2 pp; pp.x = f2bf2(v.x, v.y); pp.y = f2bf2(v.z, v.w);
    *reinterpret_cast<uint2*>(&xbf[row][colb]) = pp;
  }
  __syncthreads();

  floatx4 acc[3];
  {
    // ---- phase A: static + Q/K/V of layer 0 (B-frags = xbf, loaded once) ----
    bf16x8 bf[3][4];
    load_bfrag(&xbf[0][0], m0, qi, bf);

    proj(bf, wt, wrow, qi, acc);                 // static: relu(x@Ws+bs)
    {
      float4 b4 = *reinterpret_cast<const float4*>(bs + colb);
#pragma unroll
      for (int nt = 0; nt < 3; nt++) {
        statpk[nt][0] = f2bf2(fmaxf(acc[nt][0] + b4.x, 0.f), fmaxf(acc[nt][1] + b4.y, 0.f));
        statpk[nt][1] = f2bf2(fmaxf(acc[nt][2] + b4.z, 0.f), fmaxf(acc[nt][3] + b4.w, 0.f));
      }
    }
    proj(bf, wt + 1 * H * H, wrow, qi, acc);
    store_proj(&qbuf[0][0], acc, *reinterpret_cast<const float4*>(bq + colb), m0, colb);
    proj(bf, wt + 2 * H * H, wrow, qi, acc);
    store_proj(&kbuf[0][0], acc, *reinterpret_cast<const float4*>(bk + colb), m0, colb);
    proj(bf, wt + 3 * H * H, wrow, qi, acc);
    store_proj(&vbuf[0][0], acc, *reinterpret_cast<const float4*>(bv + colb), m0, colb);
  }
  __syncthreads();

  for (int l = 0; l < NLAYERS; l++) {
    // ---- scores + 2-way softmax (self excluded), b128-vectorized ----
    if (tid < GB * NHEADS * SG) {
      int g = tid / (NHEADS * SG);
      int rem = tid % (NHEADS * SG);
      int h = rem / SG;
      int i = rem % SG;
      int j0 = (i == 0) ? 1 : 0;
      int j1 = (i == 2) ? 1 : 2;
      const uint4* qp  = reinterpret_cast<const uint4*>(&qbuf[g * 3 + i][h * HD]);
      const uint4* k0p = reinterpret_cast<const uint4*>(&kbuf[g * 3 + j0][h * HD]);
      const uint4* k1p = reinterpret_cast<const uint4*>(&kbuf[g * 3 + j1][h * HD]);
      float s0 = 0.f, s1 = 0.f;
#pragma unroll
      for (int c = 0; c < 4; c++) {
        uint4 qu = qp[c], u0 = k0p[c], u1 = k1p[c];
        u32 qs[4] = {qu.x, qu.y, qu.z, qu.w};
        u32 a0[4] = {u0.x, u0.y, u0.z, u0.w};
        u32 a1[4] = {u1.x, u1.y, u1.z, u1.w};
#pragma unroll
        for (int e = 0; e < 4; e++) {
          float ql = bf2f_lo(qs[e]), qh = bf2f_hi(qs[e]);
          s0 += ql * bf2f_lo(a0[e]) + qh * bf2f_hi(a0[e]);
          s1 += ql * bf2f_lo(a1[e]) + qh * bf2f_hi(a1[e]);
        }
      }
      s0 *= 0.17677669529663687f;   // 1/sqrt(32)
      s1 *= 0.17677669529663687f;
      float mx = fmaxf(s0, s1);
      float e0 = __expf(s0 - mx), e1 = __expf(s1 - mx);
      float inv = 1.f / (e0 + e1);
      attnw[g][h][i][0] = e0 * inv;
      attnw[g][h][i][1] = e1 * inv;
    }
    __syncthreads();

    // ---- attention-out = attn @ V : vbuf -> qbuf, b128-vectorized ----
    for (int ch = tid; ch < MR * 16; ch += NT) {
      int r = ch >> 4, c0 = (ch & 15) << 3;
      int g = r / 3, i = r - g * 3, h = c0 >> 5;
      int j0 = (i == 0) ? 1 : 0;
      int j1 = (i == 2) ? 1 : 2;
      float a0 = attnw[g][h][i][0], a1 = attnw[g][h][i][1];
      uint4 v0 = *reinterpret_cast<const uint4*>(&vbuf[g * 3 + j0][c0]);
      uint4 v1 = *reinterpret_cast<const uint4*>(&vbuf[g * 3 + j1][c0]);
      u32 w0[4] = {v0.x, v0.y, v0.z, v0.w};
      u32 w1[4] = {v1.x, v1.y, v1.z, v1.w};
      u32 oo[4];
#pragma unroll
      for (int e = 0; e < 4; e++) {
        float lo = a0 * bf2f_lo(w0[e]) + a1 * bf2f_lo(w1[e]);
        float hi = a0 * bf2f_hi(w0[e]) + a1 * bf2f_hi(w1[e]);
        oo[e] = f2bf2(lo, hi);
      }
      uint4 o; o.x = oo[0]; o.y = oo[1]; o.z = oo[2]; o.w = oo[3];
      *reinterpret_cast<uint4*>(&qbuf[r][c0]) = o;
    }
    __syncthreads();

    // ---- O-projection + ReZero into xdyn regs ----
    {
      bf16x8 bf[3][4];
      load_bfrag(&qbuf[0][0], m0, qi, bf);
      proj(bf, wt + (size_t)(1 + l * 4 + 3) * H * H, wrow, qi, acc);
      float4 b4 = *reinterpret_cast<const float4*>(bo + l * H + colb);
      const float betal = beta[l];
#pragma unroll
      for (int nt = 0; nt < 3; nt++) {
        xdyn[nt][0] += betal * (acc[nt][0] + b4.x);
        xdyn[nt][1] += betal * (acc[nt][1] + b4.y);
        xdyn[nt][2] += betal * (acc[nt][2] + b4.z);
        xdyn[nt][3] += betal * (acc[nt][3] + b4.w);
      }
    }

    if (l + 1 < NLAYERS) {
      // refresh bf16 mirror (no reader between last barrier and here)
#pragma unroll
      for (int nt = 0; nt < 3; nt++) {
        uint2 pp;
        pp.x = f2bf2(xdyn[nt][0], xdyn[nt][1]);
        pp.y = f2bf2(xdyn[nt][2], xdyn[nt][3]);
        *reinterpret_cast<uint2*>(&xbf[nt * 16 + m0][colb]) = pp;
      }
      __syncthreads();   // xbf ready; also fences O-frag reads of qbuf

      // ---- Q/K/V of layer l+1 ----
      bf16x8 bf[3][4];
      load_bfrag(&xbf[0][0], m0, qi, bf);
      proj(bf, wt + (size_t)(1 + (l + 1) * 4 + 0) * H * H, wrow, qi, acc);
      store_proj(&qbuf[0][0], acc, *reinterpret_cast<const float4*>(bq + (l + 1) * H + colb), m0, colb);
      proj(bf, wt + (size_t)(1 + (l + 1) * 4 + 1) * H * H, wrow, qi, acc);
      store_proj(&kbuf[0][0], acc, *reinterpret_cast<const float4*>(bk + (l + 1) * H + colb), m0, colb);
      proj(bf, wt + (size_t)(1 + (l + 1) * 4 + 2) * H * H, wrow, qi, acc);
      store_proj(&vbuf[0][0], acc, *reinterpret_cast<const float4*>(bv + (l + 1) * H + colb), m0, colb);
      __syncthreads();
    }
  }

  // ---- readout: gene score = sum_c (dyn-stat)^2 * Wp[c]; group mean ----
  float4 wp4 = *reinterpret_cast<const float4*>(Wp + colb);
  float rsum[3];
#pragma unroll
  for (int nt = 0; nt < 3; nt++) {
    float d0 = xdyn[nt][0] - bf2f_lo(statpk[nt][0]);
    float d1 = xdyn[nt][1] - bf2f_hi(statpk[nt][0]);
    float d2 = xdyn[nt][2] - bf2f_lo(statpk[nt][1]);
    float d3 = xdyn[nt][3] - bf2f_hi(statpk[nt][1]);
    rsum[nt] = d0 * d0 * wp4.x + d1 * d1 * wp4.y + d2 * d2 * wp4.z + d3 * d3 * wp4.w;
  }
  // reduce over qi (lane bits 4,5): each row's 16 cols within this wave
#pragma unroll
  for (int nt = 0; nt < 3; nt++) {
    rsum[nt] += __shfl_xor(rsum[nt], 16, 64);
    rsum[nt] += __shfl_xor(rsum[nt], 32, 64);
  }
  if (qi == 0) {
#pragma unroll
    for (int nt = 0; nt < 3; nt++)
      rowsc[nt * 16 + m0][wave] = rsum[nt];
  }
  __syncthreads();
  if (tid < GB) {
    float s = 0.f;
#pragma unroll
    for (int i = 0; i < SG; i++) {
      int row = tid * 3 + i;
#pragma unroll
      for (int w = 0; w < 8; w++) s += rowsc[row][w];
    }
    out[blockIdx.x * GB + tid] = s * (1.f / 3.f) + bp[0];
  }
}

extern "C" void kernel_launch(void* const* d_in, const int* in_sizes, int n_in,
                              void* d_out, int out_size, void* d_ws, size_t ws_size,
                              hipStream_t stream) {
  const float* x    = (const float*)d_in[0];
  // d_in[1] = batch ids: deterministic repeat(arange(G),3) -> not needed
  const float* Ws   = (const float*)d_in[2];
  const float* bs   = (const float*)d_in[3];
  const float* Wq   = (const float*)d_in[4];
  const float* bq   = (const float*)d_in[5];
  const float* Wk   = (const float*)d_in[6];
  const float* bk   = (const float*)d_in[7];
  const float* Wv   = (const float*)d_in[8];
  const float* bv   = (const float*)d_in[9];
  const float* Wo   = (const float*)d_in[10];
  const float* bo   = (const float*)d_in[11];
  const float* beta = (const float*)d_in[12];
  const float* Wp   = (const float*)d_in[13];
  const float* bp   = (const float*)d_in[14];
  float* out = (float*)d_out;
  u16* wt = (u16*)d_ws;   // 9 * 128*128 bf16 = 294,912 B

  // ws is re-poisoned before every launch -> convert every call
  wconv_kernel<<<576, 256, 0, stream>>>(Ws, Wq, Wk, Wv, Wo, wt);
  dango_kernel<<<NGROUPS / GB, NT, 0, stream>>>(x, wt, bs, bq, bk, bv, bo, beta, Wp, bp, out);
}

// Round 4
// 577.418 us; speedup vs baseline: 1.1075x; 1.0552x over previous
//
#include <hip/hip_runtime.h>
#include <hip/hip_bf16.h>

#define NGROUPS 131072
#define H 128
#define SG 3            // group size
#define NHEADS 4
#define HD 32
#define GB 16           // groups per block
#define MR 48           // rows per block (= GB*SG)
#define NT 512          // threads per block (8 waves)
#define BP 136          // bf16 LDS row stride (elements); keeps b128 16B-aligned
#define NLAYERS 2

typedef unsigned short u16;
typedef unsigned int u32;
typedef __bf16 bf16x8 __attribute__((ext_vector_type(8)));
typedef float floatx4 __attribute__((ext_vector_type(4)));

__device__ __forceinline__ float bf2f_lo(u32 u) {
  union { u32 i; float f; } c; c.i = u << 16; return c.f;
}
__device__ __forceinline__ float bf2f_hi(u32 u) {
  union { u32 i; float f; } c; c.i = u & 0xffff0000u; return c.f;
}
// packed f32x2 -> bf16x2 (v_cvt_pk_bf16_f32 on gfx950), RNE
__device__ __forceinline__ u32 f2bf2(float a, float b) {
  __hip_bfloat162 h = __float22bfloat162_rn(make_float2(a, b));
  union { __hip_bfloat162 h; u32 u; } c; c.h = h; return c.u;
}
__device__ __forceinline__ u16 f2bf(float f) {
  union { float f; u32 i; } c; c.f = f;
  u32 x = c.i; x += 0x7fffu + ((x >> 16) & 1u);
  return (u16)(x >> 16);
}

// ---- weight convert + transpose: wt[slot][n][k] = W[slot][k][n] as bf16 ----
__global__ void wconv_kernel(const float* __restrict__ Ws, const float* __restrict__ Wq,
                             const float* __restrict__ Wk, const float* __restrict__ Wv,
                             const float* __restrict__ Wo, u16* __restrict__ wt) {
  int idx = blockIdx.x * 256 + threadIdx.x;      // grid sized exactly (9*16384/256)
  int slot = idx >> 14;
  int rem = idx & 16383;
  int n = rem >> 7, k = rem & 127;
  const float* src;
  if (slot == 0) src = Ws;
  else {
    int l = (slot - 1) >> 2, t = (slot - 1) & 3;
    const float* base = (t == 0) ? Wq : (t == 1) ? Wk : (t == 2) ? Wv : Wo;
    src = base + l * (H * H);
  }
  wt[idx] = f2bf(src[k * H + n]);
}

// NP projections sharing one LDS B-operand, accumulators all live (AGPR side).
// Weight slots must be consecutive (w0 + p*H*H). Streams B-frags per k-slice:
// arch-live = 12(bf) + NP*4(a, transient) instead of 48 B-frag regs.
// D[outcol=(lane>>4)*4+r][generow=lane&15]: thread owns 1 gene-row x 4 cols per nt.
template <int NP>
__device__ __forceinline__ void multi_proj(const u16* __restrict__ lds,
                                           const u16* __restrict__ w0,
                                           floatx4 acc[NP][3], int m0, int qi, int wrow) {
#pragma unroll
  for (int p = 0; p < NP; p++)
#pragma unroll
    for (int nt = 0; nt < 3; nt++)
      acc[p][nt] = (floatx4){0.f, 0.f, 0.f, 0.f};
#pragma unroll
  for (int kk = 0; kk < 4; kk++) {
    bf16x8 b[3];
#pragma unroll
    for (int nt = 0; nt < 3; nt++)
      b[nt] = *reinterpret_cast<const bf16x8*>(lds + (nt * 16 + m0) * BP + kk * 32 + qi * 8);
#pragma unroll
    for (int p = 0; p < NP; p++) {
      bf16x8 a = *reinterpret_cast<const bf16x8*>(w0 + (size_t)p * H * H + wrow * H + kk * 32 + qi * 8);
#pragma unroll
      for (int nt = 0; nt < 3; nt++)
        acc[p][nt] = __builtin_amdgcn_mfma_f32_16x16x32_bf16(a, b[nt], acc[p][nt], 0, 0, 0);
    }
  }
}

// store acc+bias as packed bf16, 4 consecutive cols per row -> one b64 write per nt
__device__ __forceinline__ void store_proj(u16* __restrict__ buf, const floatx4 acc[3],
                                           float4 b4, int m0, int colb) {
#pragma unroll
  for (int nt = 0; nt < 3; nt++) {
    uint2 pp;
    pp.x = f2bf2(acc[nt][0] + b4.x, acc[nt][1] + b4.y);
    pp.y = f2bf2(acc[nt][2] + b4.z, acc[nt][3] + b4.w);
    *reinterpret_cast<uint2*>(buf + (nt * 16 + m0) * BP + colb) = pp;
  }
}

__global__ void __launch_bounds__(NT)
__attribute__((amdgpu_waves_per_eu(4)))
dango_kernel(const float* __restrict__ x, const u16* __restrict__ wt,
             const float* __restrict__ bs, const float* __restrict__ bq,
             const float* __restrict__ bk, const float* __restrict__ bv,
             const float* __restrict__ bo, const float* __restrict__ beta,
             const float* __restrict__ Wp, const float* __restrict__ bp,
             float* __restrict__ out)
{
  // ~55.5 KB LDS -> 2 blocks/CU; 16 waves/CU at <=128 VGPR total
  __shared__ __align__(16) u16 xbf[MR][BP];   // residual bf16 mirror
  __shared__ __align__(16) u16 qbuf[MR][BP];  // Q, later attention-out
  __shared__ __align__(16) u16 kbuf[MR][BP];  // K
  __shared__ __align__(16) u16 vbuf[MR][BP];  // V
  __shared__ float attnw[GB][NHEADS][SG][2];
  __shared__ float rowsc[MR][9];

  const int tid = threadIdx.x;
  const int lane = tid & 63;
  const int wave = tid >> 6;          // 0..7: owns outcols wave*16..wave*16+15
  const int m0 = lane & 15;           // gene-row index within nt-tile
  const int qi = lane >> 4;           // 0..3: 4-col window within wave's 16
  const int colb = wave * 16 + qi * 4;
  const int wrow = wave * 16 + m0;    // weight row (outcol block) this lane loads
  const int row0 = blockIdx.x * MR;

  float xdyn[3][4];                   // residual fp32: rows nt*16+m0, cols colb..+3
  u32 statpk[3][2];                   // static embedding, packed bf16

  // ---- init: x -> xdyn regs + xbf mirror ----
#pragma unroll
  for (int nt = 0; nt < 3; nt++) {
    int row = nt * 16 + m0;
    float4 v = *reinterpret_cast<const float4*>(x + (size_t)(row0 + row) * H + colb);
    xdyn[nt][0] = v.x; xdyn[nt][1] = v.y; xdyn[nt][2] = v.z; xdyn[nt][3] = v.w;
    uint2 pp; pp.x = f2bf2(v.x, v.y); pp.y = f2bf2(v.z, v.w);
    *reinterpret_cast<uint2*>(&xbf[row][colb]) = pp;
  }
  __syncthreads();

  // ---- phase A: static + Q/K/V of layer 0, 4 acc streams, B-frags streamed ----
  {
    floatx4 acc[4][3];
    multi_proj<4>(&xbf[0][0], wt, acc, m0, qi, wrow);   // slots 0..3 = Ws,Wq0,Wk0,Wv0
    {
      float4 b4 = *reinterpret_cast<const float4*>(bs + colb);
#pragma unroll
      for (int nt = 0; nt < 3; nt++) {
        statpk[nt][0] = f2bf2(fmaxf(acc[0][nt][0] + b4.x, 0.f), fmaxf(acc[0][nt][1] + b4.y, 0.f));
        statpk[nt][1] = f2bf2(fmaxf(acc[0][nt][2] + b4.z, 0.f), fmaxf(acc[0][nt][3] + b4.w, 0.f));
      }
    }
    store_proj(&qbuf[0][0], acc[1], *reinterpret_cast<const float4*>(bq + colb), m0, colb);
    store_proj(&kbuf[0][0], acc[2], *reinterpret_cast<const float4*>(bk + colb), m0, colb);
    store_proj(&vbuf[0][0], acc[3], *reinterpret_cast<const float4*>(bv + colb), m0, colb);
  }
  __syncthreads();

  for (int l = 0; l < NLAYERS; l++) {
    // ---- scores + 2-way softmax (self excluded) ----
    if (tid < GB * NHEADS * SG) {
      int g = tid / (NHEADS * SG);
      int rem = tid % (NHEADS * SG);
      int h = rem / SG;
      int i = rem % SG;
      int j0 = (i == 0) ? 1 : 0;
      int j1 = (i == 2) ? 1 : 2;
      const uint4* qp  = reinterpret_cast<const uint4*>(&qbuf[g * 3 + i][h * HD]);
      const uint4* k0p = reinterpret_cast<const uint4*>(&kbuf[g * 3 + j0][h * HD]);
      const uint4* k1p = reinterpret_cast<const uint4*>(&kbuf[g * 3 + j1][h * HD]);
      float s0 = 0.f, s1 = 0.f;
#pragma unroll
      for (int c = 0; c < 4; c++) {
        uint4 qu = qp[c], u0 = k0p[c], u1 = k1p[c];
        u32 qs[4] = {qu.x, qu.y, qu.z, qu.w};
        u32 a0[4] = {u0.x, u0.y, u0.z, u0.w};
        u32 a1[4] = {u1.x, u1.y, u1.z, u1.w};
#pragma unroll
        for (int e = 0; e < 4; e++) {
          float ql = bf2f_lo(qs[e]), qh = bf2f_hi(qs[e]);
          s0 += ql * bf2f_lo(a0[e]) + qh * bf2f_hi(a0[e]);
          s1 += ql * bf2f_lo(a1[e]) + qh * bf2f_hi(a1[e]);
        }
      }
      s0 *= 0.17677669529663687f;   // 1/sqrt(32)
      s1 *= 0.17677669529663687f;
      float mx = fmaxf(s0, s1);
      float e0 = __expf(s0 - mx), e1 = __expf(s1 - mx);
      float inv = 1.f / (e0 + e1);
      attnw[g][h][i][0] = e0 * inv;
      attnw[g][h][i][1] = e1 * inv;
    }
    __syncthreads();

    // ---- attention-out = attn @ V : vbuf -> qbuf ----
    for (int ch = tid; ch < MR * 16; ch += NT) {
      int r = ch >> 4, c0 = (ch & 15) << 3;
      int g = r / 3, i = r - g * 3, h = c0 >> 5;
      int j0 = (i == 0) ? 1 : 0;
      int j1 = (i == 2) ? 1 : 2;
      float a0 = attnw[g][h][i][0], a1 = attnw[g][h][i][1];
      uint4 v0 = *reinterpret_cast<const uint4*>(&vbuf[g * 3 + j0][c0]);
      uint4 v1 = *reinterpret_cast<const uint4*>(&vbuf[g * 3 + j1][c0]);
      u32 w0[4] = {v0.x, v0.y, v0.z, v0.w};
      u32 w1[4] = {v1.x, v1.y, v1.z, v1.w};
      u32 oo[4];
#pragma unroll
      for (int e = 0; e < 4; e++) {
        float lo = a0 * bf2f_lo(w0[e]) + a1 * bf2f_lo(w1[e]);
        float hi = a0 * bf2f_hi(w0[e]) + a1 * bf2f_hi(w1[e]);
        oo[e] = f2bf2(lo, hi);
      }
      uint4 o; o.x = oo[0]; o.y = oo[1]; o.z = oo[2]; o.w = oo[3];
      *reinterpret_cast<uint4*>(&qbuf[r][c0]) = o;
    }
    __syncthreads();

    // ---- O-projection + ReZero into xdyn regs ----
    {
      floatx4 acc[1][3];
      multi_proj<1>(&qbuf[0][0], wt + (size_t)(1 + l * 4 + 3) * H * H, acc, m0, qi, wrow);
      float4 b4 = *reinterpret_cast<const float4*>(bo + l * H + colb);
      const float betal = beta[l];
#pragma unroll
      for (int nt = 0; nt < 3; nt++) {
        xdyn[nt][0] += betal * (acc[0][nt][0] + b4.x);
        xdyn[nt][1] += betal * (acc[0][nt][1] + b4.y);
        xdyn[nt][2] += betal * (acc[0][nt][2] + b4.z);
        xdyn[nt][3] += betal * (acc[0][nt][3] + b4.w);
      }
    }

    if (l + 1 < NLAYERS) {
      // refresh bf16 mirror (xbf has no readers in this phase)
#pragma unroll
      for (int nt = 0; nt < 3; nt++) {
        uint2 pp;
        pp.x = f2bf2(xdyn[nt][0], xdyn[nt][1]);
        pp.y = f2bf2(xdyn[nt][2], xdyn[nt][3]);
        *reinterpret_cast<uint2*>(&xbf[nt * 16 + m0][colb]) = pp;
      }
      __syncthreads();   // xbf ready; also fences O-proj's qbuf reads

      // ---- Q/K/V of layer l+1: 3 acc streams (slots consecutive) ----
      floatx4 acc[3][3];
      multi_proj<3>(&xbf[0][0], wt + (size_t)(1 + (l + 1) * 4) * H * H, acc, m0, qi, wrow);
      store_proj(&qbuf[0][0], acc[0], *reinterpret_cast<const float4*>(bq + (l + 1) * H + colb), m0, colb);
      store_proj(&kbuf[0][0], acc[1], *reinterpret_cast<const float4*>(bk + (l + 1) * H + colb), m0, colb);
      store_proj(&vbuf[0][0], acc[2], *reinterpret_cast<const float4*>(bv + (l + 1) * H + colb), m0, colb);
      __syncthreads();
    }
  }

  // ---- readout: gene score = sum_c (dyn-stat)^2 * Wp[c]; group mean ----
  float4 wp4 = *reinterpret_cast<const float4*>(Wp + colb);
  float rsum[3];
#pragma unroll
  for (int nt = 0; nt < 3; nt++) {
    float d0 = xdyn[nt][0] - bf2f_lo(statpk[nt][0]);
    float d1 = xdyn[nt][1] - bf2f_hi(statpk[nt][0]);
    float d2 = xdyn[nt][2] - bf2f_lo(statpk[nt][1]);
    float d3 = xdyn[nt][3] - bf2f_hi(statpk[nt][1]);
    rsum[nt] = d0 * d0 * wp4.x + d1 * d1 * wp4.y + d2 * d2 * wp4.z + d3 * d3 * wp4.w;
  }
  // reduce over qi (lane bits 4,5): each row's 16 cols within this wave
#pragma unroll
  for (int nt = 0; nt < 3; nt++) {
    rsum[nt] += __shfl_xor(rsum[nt], 16, 64);
    rsum[nt] += __shfl_xor(rsum[nt], 32, 64);
  }
  if (qi == 0) {
#pragma unroll
    for (int nt = 0; nt < 3; nt++)
      rowsc[nt * 16 + m0][wave] = rsum[nt];
  }
  __syncthreads();
  if (tid < GB) {
    float s = 0.f;
#pragma unroll
    for (int i = 0; i < SG; i++) {
      int row = tid * 3 + i;
#pragma unroll
      for (int w = 0; w < 8; w++) s += rowsc[row][w];
    }
    out[blockIdx.x * GB + tid] = s * (1.f / 3.f) + bp[0];
  }
}

extern "C" void kernel_launch(void* const* d_in, const int* in_sizes, int n_in,
                              void* d_out, int out_size, void* d_ws, size_t ws_size,
                              hipStream_t stream) {
  const float* x    = (const float*)d_in[0];
  // d_in[1] = batch ids: deterministic repeat(arange(G),3) -> not needed
  const float* Ws   = (const float*)d_in[2];
  const float* bs   = (const float*)d_in[3];
  const float* Wq   = (const float*)d_in[4];
  const float* bq   = (const float*)d_in[5];
  const float* Wk   = (const float*)d_in[6];
  const float* bk   = (const float*)d_in[7];
  const float* Wv   = (const float*)d_in[8];
  const float* bv   = (const float*)d_in[9];
  const float* Wo   = (const float*)d_in[10];
  const float* bo   = (const float*)d_in[11];
  const float* beta = (const float*)d_in[12];
  const float* Wp   = (const float*)d_in[13];
  const float* bp   = (const float*)d_in[14];
  float* out = (float*)d_out;
  u16* wt = (u16*)d_ws;   // 9 * 128*128 bf16 = 294,912 B

  // ws is re-poisoned before every launch -> convert every call
  wconv_kernel<<<576, 256, 0, stream>>>(Ws, Wq, Wk, Wv, Wo, wt);
  dango_kernel<<<NGROUPS / GB, NT, 0, stream>>>(x, wt, bs, bq, bk, bv, bo, beta, Wp, bp, out);
}